// Round 5
// baseline (230.584 us; speedup 1.0000x reference)
//
#include <hip/hip_runtime.h>

// SST forward for B=32, N=1048576 (fp32).
//   cA[k] = (x[2k] + x[2k+1]) * (1/sqrt(2)),  cD[k] = (x[2k] - x[2k+1]) * (1/sqrt(2))
//   d[k] = (cD<0) - (cA<0)  in {-1,0,+1}   (angle-diff clip of real-valued coeffs)
//   out[b,k,1] = cD[k]
//   out[b,k,0] = cA[k]*[d_k=0 or edge-clip] + cA[k-1]*[d_{k-1}=+1] + cA[k+1]*[d_{k+1}=-1]
// out[b,k,0:2] sits at the same flat offset as x[b,2k:2k+2] -> pointwise + radius-1 halo.
// Halo comes from adjacent lanes via __shfl; only lanes 0/63 load a 8B halo.

#define BB 32
#define NN 1048576
#define LL (NN / 2)         // 524288 pairs per row
#define TPR (LL / 4)        // 131072 tasks/row (4 pairs = 32B each) = 2^17
#define NTASK (BB * TPR)    // 4194304 tasks

__global__ __launch_bounds__(256) void sst_kernel(const float* __restrict__ x,
                                                  float* __restrict__ out) {
    const float s = 0.70710678118654752440f;
    const int lane = threadIdx.x & 63;
    const int stride = gridDim.x * blockDim.x;
    for (int c = blockIdx.x * blockDim.x + threadIdx.x; c < NTASK; c += stride) {
        const int row = c >> 17;            // c / TPR
        const int cw  = c & (TPR - 1);      // c % TPR
        const int p0  = cw << 2;            // first pair index of this task
        const float* __restrict__ rx = x   + (size_t)row * NN;
        float*       __restrict__ ro = out + (size_t)row * NN;
        const size_t off = (size_t)p0 * 2;  // float offset (32B aligned)

        const float4 m0 = *(const float4*)(rx + off);
        const float4 m1 = *(const float4*)(rx + off + 4);

        const float cA0 = (m0.x + m0.y) * s, cD0 = (m0.x - m0.y) * s;
        const float cA1 = (m0.z + m0.w) * s, cD1 = (m0.z - m0.w) * s;
        const float cA2 = (m1.x + m1.y) * s, cD2 = (m1.x - m1.y) * s;
        const float cA3 = (m1.z + m1.w) * s, cD3 = (m1.z - m1.w) * s;
        const int d0 = (cD0 < 0.f) - (cA0 < 0.f);
        const int d1 = (cD1 < 0.f) - (cA1 < 0.f);
        const int d2 = (cD2 < 0.f) - (cA2 < 0.f);
        const int d3 = (cD3 < 0.f) - (cA3 < 0.f);

        // left neighbor pair (p0-1) = lane-1's pair3; right neighbor (p0+4) = lane+1's pair0
        float cAL = __shfl_up(cA3, 1);
        int   dL  = __shfl_up(d3, 1);
        float cAR = __shfl_down(cA0, 1);
        int   dR  = __shfl_down(d0, 1);

        if (lane == 0) {                     // wave edge: real halo load (task never straddles a row)
            if (p0 > 0) {
                const float2 lp = *(const float2*)(rx + off - 2);
                const float a = (lp.x + lp.y) * s, d = (lp.x - lp.y) * s;
                cAL = a; dL = (d < 0.f) - (a < 0.f);
            } else { cAL = 0.f; dL = 0; }
        }
        if (lane == 63) {
            if (p0 + 4 < LL) {
                const float2 rp = *(const float2*)(rx + off + 8);
                const float a = (rp.x + rp.y) * s, d = (rp.x - rp.y) * s;
                cAR = a; dR = (d < 0.f) - (a < 0.f);
            } else { cAR = 0.f; dR = 0; }
        }

        const bool hasL = (p0 > 0);
        const bool hasR = (p0 + 4 < LL);
        const bool keep0 = (d0 == 0) || (p0 == 0 && d0 == -1);          // left row-edge clip
        const bool keep1 = (d1 == 0);
        const bool keep2 = (d2 == 0);
        const bool keep3 = (d3 == 0) || ((p0 + 3 == LL - 1) && d3 == 1); // right row-edge clip

        // addition order (keep + left + right) matches the verified bit-exact kernel
        const float A0 = (keep0 ? cA0 : 0.f) + ((hasL && dL == 1) ? cAL : 0.f) + ((d1 == -1) ? cA1 : 0.f);
        const float A1 = (keep1 ? cA1 : 0.f) + ((d0 == 1) ? cA0 : 0.f)        + ((d2 == -1) ? cA2 : 0.f);
        const float A2 = (keep2 ? cA2 : 0.f) + ((d1 == 1) ? cA1 : 0.f)        + ((d3 == -1) ? cA3 : 0.f);
        const float A3 = (keep3 ? cA3 : 0.f) + ((d2 == 1) ? cA2 : 0.f)        + ((hasR && dR == -1) ? cAR : 0.f);

        *(float4*)(ro + off)     = make_float4(A0, cD0, A1, cD1);
        *(float4*)(ro + off + 4) = make_float4(A2, cD2, A3, cD3);
    }
}

extern "C" void kernel_launch(void* const* d_in, const int* in_sizes, int n_in,
                              void* d_out, int out_size, void* d_ws, size_t ws_size,
                              hipStream_t stream) {
    const float* x = (const float*)d_in[0];
    float* out = (float*)d_out;
    dim3 block(256);
    dim3 grid(2048);  // 256 CU x 8 blocks/CU; grid-stride covers 4194304 tasks (8 iter/thread)
    hipLaunchKernelGGL(sst_kernel, grid, block, 0, stream, x, out);
}